// Round 1
// baseline (11.728 us; speedup 1.0000x reference)
//
#include <hip/hip_runtime.h>

// Retrace loss: reference builds W[i,j,b] = gamma^(j-i) * exp(P[j]-P[i]) (j>=i)
// and contracts it. W obeys a 1st-order linear recurrence backward in t:
//   c[t]    = gamma * exp(lw[t]),  lw = max(tlp - olp, 0)
//   R[t]    = A[t] + c[t]*R[t+1],  A = rewards - tq_traj        (R[T]=0)
//   Wsum[t] = 1    + c[t]*Wsum[t+1]                             (Wsum[T]=0)
//   retrace[t] = R[t] + tq_curr[t]*Wsum[t]
//   loss = mean((q - retrace)^2)
// => O(T*B) segmented backward scan, 6 MB input read exactly once.

constexpr int   T      = 256;
constexpr int   B      = 1024;
constexpr float GAMMA  = 0.95f;

constexpr int TILE_B = 64;        // columns per block (lane dimension -> coalesced)
constexpr int NSEG   = 16;        // row segments (one wave per segment)
constexpr int SEG    = T / NSEG;  // 16 rows per segment
constexpr int NBLK   = B / TILE_B; // 16 blocks

__global__ __launch_bounds__(TILE_B * NSEG) void retrace_main(
    const float* __restrict__ q,        // state_trajectory_action_values
    const float* __restrict__ tq_traj,  // target_state_trajectory_action_values
    const float* __restrict__ tq_curr,  // target_state_current_action_values
    const float* __restrict__ rewards,
    const float* __restrict__ olp,      // original_log_trajectory_action_probs
    const float* __restrict__ tlp,      // target_log_trajectory_task_action_probs
    float* __restrict__ partials)
{
    const int lane = threadIdx.x & 63;   // column within tile
    const int s    = threadIdx.x >> 6;   // segment id (== wave id), 0..15
    const int b    = blockIdx.x * TILE_B + lane;
    const int t0   = s * SEG;

    // ---- phase 1: per-segment backward composition  R[a] = Rp + C*R_in ----
    float cbuf[SEG], Abuf[SEG];
    float Rp = 0.f, Wp = 0.f, C = 1.f;
    #pragma unroll
    for (int k = SEG - 1; k >= 0; --k) {
        const int idx = (t0 + k) * B + b;
        float lw = tlp[idx] - olp[idx];
        lw = fmaxf(lw, 0.f);
        const float c = GAMMA * __expf(lw);
        const float A = rewards[idx] - tq_traj[idx];
        cbuf[k] = c;
        Abuf[k] = A;
        Rp = fmaf(c, Rp, A);
        Wp = fmaf(c, Wp, 1.f);
        C  = c * C;
    }

    __shared__ float sR[NSEG][TILE_B];
    __shared__ float sW[NSEG][TILE_B];
    __shared__ float sC[NSEG][TILE_B];
    __shared__ float sRin[NSEG][TILE_B];
    __shared__ float sWin[NSEG][TILE_B];

    sR[s][lane] = Rp;
    sW[s][lane] = Wp;
    sC[s][lane] = C;
    __syncthreads();

    // ---- phase 2: serial combine over the 16 segments (wave 0, lane=column) ----
    if (s == 0) {
        float Rin = 0.f, Win = 0.f;
        #pragma unroll
        for (int ss = NSEG - 1; ss >= 0; --ss) {
            sRin[ss][lane] = Rin;
            sWin[ss][lane] = Win;
            const float cc = sC[ss][lane];
            Rin = fmaf(cc, Rin, sR[ss][lane]);
            Win = fmaf(cc, Win, sW[ss][lane]);
        }
    }
    __syncthreads();

    // ---- phase 3: replay segment with carry, accumulate squared error ----
    float R = sRin[s][lane];
    float W = sWin[s][lane];
    float acc = 0.f;
    #pragma unroll
    for (int k = SEG - 1; k >= 0; --k) {
        const int idx = (t0 + k) * B + b;
        R = fmaf(cbuf[k], R, Abuf[k]);
        W = fmaf(cbuf[k], W, 1.f);
        const float retrace = fmaf(tq_curr[idx], W, R);
        const float d = q[idx] - retrace;
        acc = fmaf(d, d, acc);
    }

    // ---- block reduction (deterministic) ----
    #pragma unroll
    for (int off = 32; off > 0; off >>= 1)
        acc += __shfl_down(acc, off, 64);

    __shared__ float swsum[NSEG];
    if (lane == 0) swsum[s] = acc;
    __syncthreads();
    if (threadIdx.x == 0) {
        float tsum = 0.f;
        #pragma unroll
        for (int i = 0; i < NSEG; ++i) tsum += swsum[i];
        partials[blockIdx.x] = tsum;
    }
}

__global__ void retrace_final(const float* __restrict__ partials,
                              float* __restrict__ out)
{
    if (threadIdx.x == 0) {
        float tsum = 0.f;
        #pragma unroll
        for (int i = 0; i < NBLK; ++i) tsum += partials[i];
        out[0] = tsum / (float)(T * B);
    }
}

extern "C" void kernel_launch(void* const* d_in, const int* in_sizes, int n_in,
                              void* d_out, int out_size, void* d_ws, size_t ws_size,
                              hipStream_t stream)
{
    const float* q       = (const float*)d_in[0];
    const float* tq_traj = (const float*)d_in[1];
    const float* tq_curr = (const float*)d_in[2];
    const float* rewards = (const float*)d_in[3];
    const float* olp     = (const float*)d_in[4];
    const float* tlp     = (const float*)d_in[5];

    float* partials = (float*)d_ws;   // NBLK floats
    float* out      = (float*)d_out;

    retrace_main<<<NBLK, TILE_B * NSEG, 0, stream>>>(
        q, tq_traj, tq_curr, rewards, olp, tlp, partials);
    retrace_final<<<1, 64, 0, stream>>>(partials, out);
}